// Round 4
// baseline (222.274 us; speedup 1.0000x reference)
//
#include <hip/hip_runtime.h>
#include <hip/hip_bf16.h>

#define DP    257
#define NP    2049
#define NSEQ  2048
#define NB    16
#define KLD   288          // padded k-dim / leading dim for small matrices (9*32)
#define HROWS 320          // padded rows for Hb (allows 64-row B-tiles)
#define TROWS 2176         // padded t rows for Hbt (17*128)

typedef __attribute__((ext_vector_type(8))) short bf16x8;
typedef __attribute__((ext_vector_type(4))) short bf16x4;
typedef __attribute__((ext_vector_type(4))) float f32x4;

// ---------------------------------------------------------------------------
// Convert H -> Hb (row-major bf16, 320 rows x 2048 cols, = masked H-hat)
//           -> Hbt (transposed bf16, 2176 rows x 288 cols, zero-padded)
// ---------------------------------------------------------------------------
__global__ __launch_bounds__(256) void conv_h(const float* __restrict__ H,
                                              __hip_bfloat16* __restrict__ Hb,
                                              __hip_bfloat16* __restrict__ Hbt) {
    const int b  = blockIdx.z;
    const int t0 = blockIdx.x * 64;
    const int e0 = blockIdx.y * 64;
    const float* __restrict__ Hs = H + (size_t)b * DP * NP;
    __hip_bfloat16* __restrict__ Hbb  = Hb  + (size_t)b * HROWS * 2048;
    __hip_bfloat16* __restrict__ Hbtb = Hbt + (size_t)b * TROWS * KLD;

    __shared__ float tile[64][65];

    const int tl = threadIdx.x & 63;
    const int er = threadIdx.x >> 6;
#pragma unroll
    for (int r = 0; r < 16; ++r) {
        const int el = er + r * 4;        // 0..63
        const int ge = e0 + el;
        const int gt = t0 + tl;
        float v = 0.f;
        if (ge < DP && gt < NP) v = Hs[(size_t)ge * NP + gt];
        tile[el][tl] = v;
        if (ge < HROWS && gt < 2048) Hbb[(size_t)ge * 2048 + gt] = __float2bfloat16(v);
    }
    __syncthreads();
#pragma unroll
    for (int r = 0; r < 16; ++r) {
        const int ttl = er + r * 4;       // t-local
        const int gt = t0 + ttl;
        const int ge = e0 + tl;           // e-local = lane -> contiguous writes
        if (gt < TROWS && ge < KLD)
            Hbtb[(size_t)gt * KLD + ge] = __float2bfloat16(tile[tl][ttl]);
    }
}

// ---------------------------------------------------------------------------
// Pb[m][k] = P[m][k] (bf16, zero-padded to 288x288); Qt[n][k] = Q[k][n]
// ---------------------------------------------------------------------------
__global__ __launch_bounds__(256) void conv_pq(const float* __restrict__ P,
                                               const float* __restrict__ Q,
                                               __hip_bfloat16* __restrict__ Pb,
                                               __hip_bfloat16* __restrict__ Qt) {
    const int c0 = blockIdx.x * 64;
    const int r0 = blockIdx.y * 64;
    const int tl = threadIdx.x & 63;
    const int rr = threadIdx.x >> 6;
    __shared__ float tile[64][65];

    if (blockIdx.z == 0) {
#pragma unroll
        for (int r = 0; r < 16; ++r) {
            const int m = r0 + rr + r * 4;
            const int k = c0 + tl;
            float v = (m < DP && k < DP) ? P[m * DP + k] : 0.f;
            if (m < KLD && k < KLD) Pb[m * KLD + k] = __float2bfloat16(v);
        }
    } else {
#pragma unroll
        for (int r = 0; r < 16; ++r) {
            const int k = r0 + rr + r * 4;
            const int n = c0 + tl;
            float v = (k < DP && n < DP) ? Q[k * DP + n] : 0.f;
            tile[k - r0][n - c0] = v;
        }
        __syncthreads();
#pragma unroll
        for (int r = 0; r < 16; ++r) {
            const int k = r0 + tl;
            const int n = c0 + rr + r * 4;
            if (n < KLD && k < KLD) Qt[n * KLD + k] = __float2bfloat16(tile[tl][n - c0]);
        }
    }
}

// ---------------------------------------------------------------------------
// G[b] = Hb[b] @ Hb[b]^T  with split-K x4 and 32(m) x 64(n) wave tiles.
// Block = one 32x64 output tile; wave s covers k in [s*512, s*512+512);
// partials summed via LDS; bf16x8 vector stores.
// ---------------------------------------------------------------------------
__global__ __launch_bounds__(256) void gram_sk(const __hip_bfloat16* __restrict__ Hb,
                                               __hip_bfloat16* __restrict__ G) {
    const int b  = blockIdx.y;
    const int tm = blockIdx.x / 5;        // 0..8  (m tile of 32)
    const int tn = blockIdx.x % 5;        // 0..4  (n tile of 64)
    const int s    = threadIdx.x >> 6;    // k-split id = wave id
    const int lane = threadIdx.x & 63;
    const int lrow = lane & 15;
    const int koff = (lane >> 4) * 8;
    const short* __restrict__ base = (const short*)(Hb + (size_t)b * HROWS * 2048);
    const int m0 = tm * 32, n0 = tn * 64;

    __shared__ float red[4][32][64];      // 32 KB

    f32x4 acc[2][4] = {};
    const int kbeg = s * 512;
#pragma unroll 4
    for (int k0 = kbeg; k0 < kbeg + 512; k0 += 32) {
        bf16x8 a0 = *(const bf16x8*)(base + (size_t)(m0 + lrow)      * 2048 + k0 + koff);
        bf16x8 a1 = *(const bf16x8*)(base + (size_t)(m0 + 16 + lrow) * 2048 + k0 + koff);
        bf16x8 bb[4];
#pragma unroll
        for (int j = 0; j < 4; ++j)
            bb[j] = *(const bf16x8*)(base + (size_t)(n0 + j * 16 + lrow) * 2048 + k0 + koff);
#pragma unroll
        for (int j = 0; j < 4; ++j) {
            acc[0][j] = __builtin_amdgcn_mfma_f32_16x16x32_bf16(a0, bb[j], acc[0][j], 0, 0, 0);
            acc[1][j] = __builtin_amdgcn_mfma_f32_16x16x32_bf16(a1, bb[j], acc[1][j], 0, 0, 0);
        }
    }

    const int ccol  = lane & 15;
    const int crow0 = (lane >> 4) * 4;
#pragma unroll
    for (int i = 0; i < 2; ++i)
#pragma unroll
        for (int j = 0; j < 4; ++j)
#pragma unroll
            for (int r = 0; r < 4; ++r)
                red[s][i * 16 + crow0 + r][j * 16 + ccol] = acc[i][j][r];
    __syncthreads();

    // 256 threads: each sums 8 consecutive cols of one row across the 4 splits
    const int row = threadIdx.x >> 3;          // 0..31
    const int c8  = (threadIdx.x & 7) * 8;     // 0..56
    float sum[8];
#pragma unroll
    for (int h = 0; h < 2; ++h) {
        float4 v0 = *(const float4*)&red[0][row][c8 + h * 4];
        float4 v1 = *(const float4*)&red[1][row][c8 + h * 4];
        float4 v2 = *(const float4*)&red[2][row][c8 + h * 4];
        float4 v3 = *(const float4*)&red[3][row][c8 + h * 4];
        sum[h * 4 + 0] = v0.x + v1.x + v2.x + v3.x;
        sum[h * 4 + 1] = v0.y + v1.y + v2.y + v3.y;
        sum[h * 4 + 2] = v0.z + v1.z + v2.z + v3.z;
        sum[h * 4 + 3] = v0.w + v1.w + v2.w + v3.w;
    }

    const int gm = m0 + row;
    const int gn = n0 + c8;
    __hip_bfloat16* __restrict__ Gb = G + (size_t)b * KLD * KLD;
    __hip_bfloat16 o[8];
#pragma unroll
    for (int t = 0; t < 8; ++t) {
        const float v = (gm < DP && (gn + t) < DP) ? sum[t] : 0.f;
        o[t] = __float2bfloat16(v);
    }
    if (gn + 7 < KLD) {
        *(bf16x4*)&Gb[gm * KLD + gn]     = *(const bf16x4*)&o[0];
        *(bf16x4*)&Gb[gm * KLD + gn + 4] = *(const bf16x4*)&o[4];
    }
    // gn >= 288: out of padded range, nothing to store
}

// ---------------------------------------------------------------------------
// Kb[b] = P @ G[b] @ Q, fused. Block = (m-tile of 32, b), 4 waves.
// Stage 1: W = P_tile @ G  (B-frags = G rows, valid by symmetry) -> LDS bf16.
// Stage 2: Kb_tile = W @ Q (A-frags from LDS, B-frags = Qt rows).
// ---------------------------------------------------------------------------
__global__ __launch_bounds__(256) void pgq_kernel(const __hip_bfloat16* __restrict__ Pb,
                                                  const __hip_bfloat16* __restrict__ Qt,
                                                  const __hip_bfloat16* __restrict__ G,
                                                  __hip_bfloat16* __restrict__ Kb) {
    const int mt = blockIdx.x;            // 0..8
    const int b  = blockIdx.y;
    const int wave = threadIdx.x >> 6;
    const int lane = threadIdx.x & 63;
    const int lrow = lane & 15;
    const int koff = (lane >> 4) * 8;
    const int ccol  = lane & 15;
    const int crow0 = (lane >> 4) * 4;
    const int m0 = mt * 32;

    const short* __restrict__ Ps = (const short*)Pb;
    const short* __restrict__ Qs = (const short*)Qt;
    const short* __restrict__ Gs = (const short*)(G + (size_t)b * KLD * KLD);

    __shared__ short W[9][32][32];        // W = P_tile @ G, tile-blocked bf16 (18.4 KB)

    // ---- stage 1 ----
    for (int jt = wave; jt < 9; jt += 4) {
        const int n0 = jt * 32;
        f32x4 acc[2][2] = {};
#pragma unroll
        for (int k0 = 0; k0 < KLD; k0 += 32) {
            bf16x8 a0 = *(const bf16x8*)(Ps + (m0 + lrow)      * KLD + k0 + koff);
            bf16x8 a1 = *(const bf16x8*)(Ps + (m0 + 16 + lrow) * KLD + k0 + koff);
            bf16x8 c0 = *(const bf16x8*)(Gs + (n0 + lrow)      * KLD + k0 + koff);
            bf16x8 c1 = *(const bf16x8*)(Gs + (n0 + 16 + lrow) * KLD + k0 + koff);
            acc[0][0] = __builtin_amdgcn_mfma_f32_16x16x32_bf16(a0, c0, acc[0][0], 0, 0, 0);
            acc[0][1] = __builtin_amdgcn_mfma_f32_16x16x32_bf16(a0, c1, acc[0][1], 0, 0, 0);
            acc[1][0] = __builtin_amdgcn_mfma_f32_16x16x32_bf16(a1, c0, acc[1][0], 0, 0, 0);
            acc[1][1] = __builtin_amdgcn_mfma_f32_16x16x32_bf16(a1, c1, acc[1][1], 0, 0, 0);
        }
#pragma unroll
        for (int i = 0; i < 2; ++i)
#pragma unroll
            for (int j = 0; j < 2; ++j)
#pragma unroll
                for (int r = 0; r < 4; ++r) {
                    __hip_bfloat16 h = __float2bfloat16(acc[i][j][r]);
                    W[jt][i * 16 + crow0 + r][j * 16 + ccol] = *(const short*)&h;
                }
    }
    __syncthreads();

    // ---- stage 2 ----
    __hip_bfloat16* __restrict__ Kbb = Kb + (size_t)b * KLD * KLD;
    for (int nt = wave; nt < 9; nt += 4) {
        const int n0 = nt * 32;
        f32x4 acc[2][2] = {};
#pragma unroll
        for (int kt = 0; kt < 9; ++kt) {
            bf16x8 a0 = *(const bf16x8*)&W[kt][lrow][koff];
            bf16x8 a1 = *(const bf16x8*)&W[kt][16 + lrow][koff];
            bf16x8 c0 = *(const bf16x8*)(Qs + (n0 + lrow)      * KLD + kt * 32 + koff);
            bf16x8 c1 = *(const bf16x8*)(Qs + (n0 + 16 + lrow) * KLD + kt * 32 + koff);
            acc[0][0] = __builtin_amdgcn_mfma_f32_16x16x32_bf16(a0, c0, acc[0][0], 0, 0, 0);
            acc[0][1] = __builtin_amdgcn_mfma_f32_16x16x32_bf16(a0, c1, acc[0][1], 0, 0, 0);
            acc[1][0] = __builtin_amdgcn_mfma_f32_16x16x32_bf16(a1, c0, acc[1][0], 0, 0, 0);
            acc[1][1] = __builtin_amdgcn_mfma_f32_16x16x32_bf16(a1, c1, acc[1][1], 0, 0, 0);
        }
#pragma unroll
        for (int i = 0; i < 2; ++i)
#pragma unroll
            for (int j = 0; j < 2; ++j)
#pragma unroll
                for (int r = 0; r < 4; ++r) {
                    const int gm = m0 + i * 16 + crow0 + r;
                    const int gn = n0 + j * 16 + ccol;
                    const float v = (gm < DP && gn < DP) ? acc[i][j][r] : 0.f;
                    Kbb[gm * KLD + gn] = __float2bfloat16(v);
                }
    }
}

// ---------------------------------------------------------------------------
// out[b][d][t] = H[b][d][t] + (1/n) * sum_e Kb[d][e] * Hbt[t][e]
// One wave per 32(d) x 128(t) tile: 2 a-frags + 8 b-frags -> 16 MFMA / k-step.
// ---------------------------------------------------------------------------
__global__ __launch_bounds__(256) void attn_mfma(const __hip_bfloat16* __restrict__ Kb,
                                                 const __hip_bfloat16* __restrict__ Hbt,
                                                 const float* __restrict__ H,
                                                 float* __restrict__ Out) {
    const int gw   = blockIdx.x * 4 + (threadIdx.x >> 6);
    const int b    = gw / 153;            // 153 = 9 (d-tiles of 32) * 17 (t-tiles of 128)
    const int tile = gw % 153;
    const int td = tile / 17, tt = tile % 17;
    const int lane = threadIdx.x & 63;
    const int lrow = lane & 15;
    const int koff = (lane >> 4) * 8;
    const short* __restrict__ Ab = (const short*)(Kb  + (size_t)b * KLD * KLD);
    const short* __restrict__ Bb = (const short*)(Hbt + (size_t)b * TROWS * KLD);
    const int m0 = td * 32, n0 = tt * 128;

    f32x4 acc[2][8] = {};
#pragma unroll 3
    for (int k0 = 0; k0 < KLD; k0 += 32) {
        bf16x8 a0 = *(const bf16x8*)(Ab + (m0 + lrow)      * KLD + k0 + koff);
        bf16x8 a1 = *(const bf16x8*)(Ab + (m0 + 16 + lrow) * KLD + k0 + koff);
        bf16x8 bb[8];
#pragma unroll
        for (int j = 0; j < 8; ++j)
            bb[j] = *(const bf16x8*)(Bb + (size_t)(n0 + j * 16 + lrow) * KLD + k0 + koff);
#pragma unroll
        for (int j = 0; j < 8; ++j) {
            acc[0][j] = __builtin_amdgcn_mfma_f32_16x16x32_bf16(a0, bb[j], acc[0][j], 0, 0, 0);
            acc[1][j] = __builtin_amdgcn_mfma_f32_16x16x32_bf16(a1, bb[j], acc[1][j], 0, 0, 0);
        }
    }
    const float* __restrict__ Hs = H + (size_t)b * DP * NP;
    float* __restrict__ Ob = Out + (size_t)b * DP * NP;
    const float inv_n = 1.0f / (float)NSEQ;
    const int ccol  = lane & 15;
    const int crow0 = (lane >> 4) * 4;
#pragma unroll
    for (int i = 0; i < 2; ++i)
#pragma unroll
        for (int j = 0; j < 8; ++j)
#pragma unroll
            for (int r = 0; r < 4; ++r) {
                const int gd = m0 + i * 16 + crow0 + r;
                const int gt = n0 + j * 16 + ccol;
                if (gd < DP && gt < NP) {
                    const size_t idx = (size_t)gd * NP + gt;
                    Ob[idx] = Hs[idx] + inv_n * acc[i][j][r];
                }
            }
}

extern "C" void kernel_launch(void* const* d_in, const int* in_sizes, int n_in,
                              void* d_out, int out_size, void* d_ws, size_t ws_size,
                              hipStream_t stream) {
    const float* H = (const float*)d_in[0];
    const float* P = (const float*)d_in[1];
    const float* Q = (const float*)d_in[2];
    float* out = (float*)d_out;

    __hip_bfloat16* Hb  = (__hip_bfloat16*)d_ws;                   // 16*320*2048
    __hip_bfloat16* Hbt = Hb  + (size_t)NB * HROWS * 2048;         // 16*2176*288
    __hip_bfloat16* G   = Hbt + (size_t)NB * TROWS * KLD;          // 16*288*288
    __hip_bfloat16* Kb  = G   + (size_t)NB * KLD * KLD;            // 16*288*288
    __hip_bfloat16* Pb  = Kb  + (size_t)NB * KLD * KLD;            // 288*288
    __hip_bfloat16* Qt  = Pb  + (size_t)KLD * KLD;                 // 288*288

    conv_h <<<dim3(34, 5, NB), 256, 0, stream>>>(H, Hb, Hbt);
    conv_pq<<<dim3(5, 5, 2),   256, 0, stream>>>(P, Q, Pb, Qt);
    // G[b] = H-hat @ H-hat^T  (split-K x4, 32x64 tiles, in-block reduce)
    gram_sk<<<dim3(45, NB), 256, 0, stream>>>(Hb, G);
    // Kb[b] = P @ G[b] @ Q  (fused two-stage, W through LDS)
    pgq_kernel<<<dim3(9, NB), 256, 0, stream>>>(Pb, Qt, G, Kb);
    // out = H + (Kb @ H) / n
    attn_mfma<<<dim3(612), 256, 0, stream>>>(Kb, Hbt, H, out);
}

// Round 5
// 215.899 us; speedup vs baseline: 1.0295x; 1.0295x over previous
//
#include <hip/hip_runtime.h>
#include <hip/hip_bf16.h>

#define DP    257
#define NP    2049
#define NSEQ  2048
#define NB    16
#define KLD   288          // padded k-dim / leading dim for small matrices (9*32)
#define HROWS 320          // padded rows for Hb
#define TROWS 2112         // padded t rows for Hbt (33*64)

typedef __attribute__((ext_vector_type(8))) short bf16x8;
typedef __attribute__((ext_vector_type(4))) short bf16x4;
typedef __attribute__((ext_vector_type(4))) float f32x4;

// ---------------------------------------------------------------------------
// Convert H -> Hb (row-major bf16, 320 rows x 2048 cols, = masked H-hat)
//           -> Hbt (transposed bf16, 2112 rows x 288 cols, zero-padded)
// ---------------------------------------------------------------------------
__global__ __launch_bounds__(256) void conv_h(const float* __restrict__ H,
                                              __hip_bfloat16* __restrict__ Hb,
                                              __hip_bfloat16* __restrict__ Hbt) {
    const int b  = blockIdx.z;
    const int t0 = blockIdx.x * 64;
    const int e0 = blockIdx.y * 64;
    const float* __restrict__ Hs = H + (size_t)b * DP * NP;
    __hip_bfloat16* __restrict__ Hbb  = Hb  + (size_t)b * HROWS * 2048;
    __hip_bfloat16* __restrict__ Hbtb = Hbt + (size_t)b * TROWS * KLD;

    __shared__ float tile[64][65];

    const int tl = threadIdx.x & 63;
    const int er = threadIdx.x >> 6;
#pragma unroll
    for (int r = 0; r < 16; ++r) {
        const int el = er + r * 4;        // 0..63
        const int ge = e0 + el;
        const int gt = t0 + tl;
        float v = 0.f;
        if (ge < DP && gt < NP) v = Hs[(size_t)ge * NP + gt];
        tile[el][tl] = v;
        if (ge < HROWS && gt < 2048) Hbb[(size_t)ge * 2048 + gt] = __float2bfloat16(v);
    }
    __syncthreads();
#pragma unroll
    for (int r = 0; r < 16; ++r) {
        const int ttl = er + r * 4;       // t-local
        const int gt = t0 + ttl;
        const int ge = e0 + tl;           // e-local = lane -> contiguous writes
        if (gt < TROWS && ge < KLD)
            Hbtb[(size_t)gt * KLD + ge] = __float2bfloat16(tile[tl][ttl]);
    }
}

// ---------------------------------------------------------------------------
// Pb[m][k] = P[m][k] (bf16, zero-padded to 288x288); Qt[n][k] = Q[k][n]
// ---------------------------------------------------------------------------
__global__ __launch_bounds__(256) void conv_pq(const float* __restrict__ P,
                                               const float* __restrict__ Q,
                                               __hip_bfloat16* __restrict__ Pb,
                                               __hip_bfloat16* __restrict__ Qt) {
    const int c0 = blockIdx.x * 64;
    const int r0 = blockIdx.y * 64;
    const int tl = threadIdx.x & 63;
    const int rr = threadIdx.x >> 6;
    __shared__ float tile[64][65];

    if (blockIdx.z == 0) {
#pragma unroll
        for (int r = 0; r < 16; ++r) {
            const int m = r0 + rr + r * 4;
            const int k = c0 + tl;
            float v = (m < DP && k < DP) ? P[m * DP + k] : 0.f;
            if (m < KLD && k < KLD) Pb[m * KLD + k] = __float2bfloat16(v);
        }
    } else {
#pragma unroll
        for (int r = 0; r < 16; ++r) {
            const int k = r0 + rr + r * 4;
            const int n = c0 + tl;
            float v = (k < DP && n < DP) ? Q[k * DP + n] : 0.f;
            tile[k - r0][n - c0] = v;
        }
        __syncthreads();
#pragma unroll
        for (int r = 0; r < 16; ++r) {
            const int k = r0 + tl;
            const int n = c0 + rr + r * 4;
            if (n < KLD && k < KLD) Qt[n * KLD + k] = __float2bfloat16(tile[tl][n - c0]);
        }
    }
}

// ---------------------------------------------------------------------------
// G[b] = Hb[b] @ Hb[b]^T  with split-K x8: 512-thread blocks, one block per
// 32x32 output tile; wave s covers k in [s*256, s*256+256) (8 steps);
// 8 partial tiles summed via LDS; packed bf16x2 stores.
// ---------------------------------------------------------------------------
__global__ __launch_bounds__(512) void gram_sk8(const __hip_bfloat16* __restrict__ Hb,
                                                __hip_bfloat16* __restrict__ G) {
    const int b  = blockIdx.y;
    const int tm = blockIdx.x / 9;
    const int tn = blockIdx.x % 9;
    const int s    = threadIdx.x >> 6;     // k-split id = wave id (0..7)
    const int lane = threadIdx.x & 63;
    const int lrow = lane & 15;
    const int koff = (lane >> 4) * 8;
    const short* __restrict__ base = (const short*)(Hb + (size_t)b * HROWS * 2048);
    const int m0 = tm * 32, n0 = tn * 32;

    __shared__ float red[8][32][32];       // 32 KB

    f32x4 acc[2][2] = {};
    const int kbeg = s * 256;
#pragma unroll 4
    for (int k0 = kbeg; k0 < kbeg + 256; k0 += 32) {
        bf16x8 a0 = *(const bf16x8*)(base + (size_t)(m0 + lrow)      * 2048 + k0 + koff);
        bf16x8 a1 = *(const bf16x8*)(base + (size_t)(m0 + 16 + lrow) * 2048 + k0 + koff);
        bf16x8 c0 = *(const bf16x8*)(base + (size_t)(n0 + lrow)      * 2048 + k0 + koff);
        bf16x8 c1 = *(const bf16x8*)(base + (size_t)(n0 + 16 + lrow) * 2048 + k0 + koff);
        acc[0][0] = __builtin_amdgcn_mfma_f32_16x16x32_bf16(a0, c0, acc[0][0], 0, 0, 0);
        acc[0][1] = __builtin_amdgcn_mfma_f32_16x16x32_bf16(a0, c1, acc[0][1], 0, 0, 0);
        acc[1][0] = __builtin_amdgcn_mfma_f32_16x16x32_bf16(a1, c0, acc[1][0], 0, 0, 0);
        acc[1][1] = __builtin_amdgcn_mfma_f32_16x16x32_bf16(a1, c1, acc[1][1], 0, 0, 0);
    }

    const int ccol  = lane & 15;
    const int crow0 = (lane >> 4) * 4;
#pragma unroll
    for (int i = 0; i < 2; ++i)
#pragma unroll
        for (int j = 0; j < 2; ++j)
#pragma unroll
            for (int r = 0; r < 4; ++r)
                red[s][i * 16 + crow0 + r][j * 16 + ccol] = acc[i][j][r];
    __syncthreads();

    // 512 threads: each sums 2 consecutive cols of one row across the 8 splits
    const int row = threadIdx.x >> 4;           // 0..31
    const int c2  = (threadIdx.x & 15) * 2;     // 0..30
    float s0 = 0.f, s1 = 0.f;
#pragma unroll
    for (int ss = 0; ss < 8; ++ss) {
        s0 += red[ss][row][c2];
        s1 += red[ss][row][c2 + 1];
    }
    const int gm = m0 + row;
    const int gn = n0 + c2;
    const float v0 = (gm < DP && gn     < DP) ? s0 : 0.f;
    const float v1 = (gm < DP && gn + 1 < DP) ? s1 : 0.f;
    __hip_bfloat16 o0 = __float2bfloat16(v0);
    __hip_bfloat16 o1 = __float2bfloat16(v1);
    const unsigned int pk = (unsigned int)*(unsigned short*)&o0 |
                            ((unsigned int)*(unsigned short*)&o1 << 16);
    __hip_bfloat16* __restrict__ Gb = G + (size_t)b * KLD * KLD;
    *(unsigned int*)&Gb[gm * KLD + gn] = pk;
}

// ---------------------------------------------------------------------------
// Kb[b] = P @ G[b] @ Q, fused. Block = (m-tile of 32, b), 4 waves.
// Stage 1: W = P_tile @ G  (B-frags = G rows, valid by symmetry) -> LDS bf16.
// Stage 2: Kb_tile = W @ Q (A-frags from LDS, B-frags = Qt rows).
// ---------------------------------------------------------------------------
__global__ __launch_bounds__(256) void pgq_kernel(const __hip_bfloat16* __restrict__ Pb,
                                                  const __hip_bfloat16* __restrict__ Qt,
                                                  const __hip_bfloat16* __restrict__ G,
                                                  __hip_bfloat16* __restrict__ Kb) {
    const int mt = blockIdx.x;            // 0..8
    const int b  = blockIdx.y;
    const int wave = threadIdx.x >> 6;
    const int lane = threadIdx.x & 63;
    const int lrow = lane & 15;
    const int koff = (lane >> 4) * 8;
    const int ccol  = lane & 15;
    const int crow0 = (lane >> 4) * 4;
    const int m0 = mt * 32;

    const short* __restrict__ Ps = (const short*)Pb;
    const short* __restrict__ Qs = (const short*)Qt;
    const short* __restrict__ Gs = (const short*)(G + (size_t)b * KLD * KLD);

    __shared__ short W[9][32][32];        // W = P_tile @ G, tile-blocked bf16 (18.4 KB)

    // ---- stage 1 ----
    for (int jt = wave; jt < 9; jt += 4) {
        const int n0 = jt * 32;
        f32x4 acc[2][2] = {};
#pragma unroll
        for (int k0 = 0; k0 < KLD; k0 += 32) {
            bf16x8 a0 = *(const bf16x8*)(Ps + (m0 + lrow)      * KLD + k0 + koff);
            bf16x8 a1 = *(const bf16x8*)(Ps + (m0 + 16 + lrow) * KLD + k0 + koff);
            bf16x8 c0 = *(const bf16x8*)(Gs + (n0 + lrow)      * KLD + k0 + koff);
            bf16x8 c1 = *(const bf16x8*)(Gs + (n0 + 16 + lrow) * KLD + k0 + koff);
            acc[0][0] = __builtin_amdgcn_mfma_f32_16x16x32_bf16(a0, c0, acc[0][0], 0, 0, 0);
            acc[0][1] = __builtin_amdgcn_mfma_f32_16x16x32_bf16(a0, c1, acc[0][1], 0, 0, 0);
            acc[1][0] = __builtin_amdgcn_mfma_f32_16x16x32_bf16(a1, c0, acc[1][0], 0, 0, 0);
            acc[1][1] = __builtin_amdgcn_mfma_f32_16x16x32_bf16(a1, c1, acc[1][1], 0, 0, 0);
        }
#pragma unroll
        for (int i = 0; i < 2; ++i)
#pragma unroll
            for (int j = 0; j < 2; ++j)
#pragma unroll
                for (int r = 0; r < 4; ++r) {
                    __hip_bfloat16 h = __float2bfloat16(acc[i][j][r]);
                    W[jt][i * 16 + crow0 + r][j * 16 + ccol] = *(const short*)&h;
                }
    }
    __syncthreads();

    // ---- stage 2 ----
    __hip_bfloat16* __restrict__ Kbb = Kb + (size_t)b * KLD * KLD;
    for (int nt = wave; nt < 9; nt += 4) {
        const int n0 = nt * 32;
        f32x4 acc[2][2] = {};
#pragma unroll
        for (int kt = 0; kt < 9; ++kt) {
            bf16x8 a0 = *(const bf16x8*)&W[kt][lrow][koff];
            bf16x8 a1 = *(const bf16x8*)&W[kt][16 + lrow][koff];
            bf16x8 c0 = *(const bf16x8*)(Qs + (n0 + lrow)      * KLD + kt * 32 + koff);
            bf16x8 c1 = *(const bf16x8*)(Qs + (n0 + 16 + lrow) * KLD + kt * 32 + koff);
            acc[0][0] = __builtin_amdgcn_mfma_f32_16x16x32_bf16(a0, c0, acc[0][0], 0, 0, 0);
            acc[0][1] = __builtin_amdgcn_mfma_f32_16x16x32_bf16(a0, c1, acc[0][1], 0, 0, 0);
            acc[1][0] = __builtin_amdgcn_mfma_f32_16x16x32_bf16(a1, c0, acc[1][0], 0, 0, 0);
            acc[1][1] = __builtin_amdgcn_mfma_f32_16x16x32_bf16(a1, c1, acc[1][1], 0, 0, 0);
        }
#pragma unroll
        for (int i = 0; i < 2; ++i)
#pragma unroll
            for (int j = 0; j < 2; ++j)
#pragma unroll
                for (int r = 0; r < 4; ++r) {
                    const int gm = m0 + i * 16 + crow0 + r;
                    const int gn = n0 + j * 16 + ccol;
                    const float v = (gm < DP && gn < DP) ? acc[i][j][r] : 0.f;
                    Kbb[gm * KLD + gn] = __float2bfloat16(v);
                }
    }
}

// ---------------------------------------------------------------------------
// out[b][d][t] = H[b][d][t] + (1/n) * sum_e Kb[d][e] * Hbt[t][e]
// One wave per 32(d) x 64(t) tile: 2 a-frags + 4 b-frags -> 8 MFMA / k-step.
// (Round-3 proven config: VGPR 56, 1188 blocks.)
// ---------------------------------------------------------------------------
__global__ __launch_bounds__(256) void attn_mfma(const __hip_bfloat16* __restrict__ Kb,
                                                 const __hip_bfloat16* __restrict__ Hbt,
                                                 const float* __restrict__ H,
                                                 float* __restrict__ Out) {
    const int gw   = blockIdx.x * 4 + (threadIdx.x >> 6);
    const int b    = gw / 297;            // 297 = 9 (d-tiles of 32) * 33 (t-tiles of 64)
    const int tile = gw % 297;
    const int td = tile / 33, tt = tile % 33;
    const int lane = threadIdx.x & 63;
    const int lrow = lane & 15;
    const int koff = (lane >> 4) * 8;
    const short* __restrict__ Ab = (const short*)(Kb  + (size_t)b * KLD * KLD);
    const short* __restrict__ Bb = (const short*)(Hbt + (size_t)b * TROWS * KLD);
    const int m0 = td * 32, n0 = tt * 64;

    f32x4 acc[2][4] = {};
#pragma unroll 3
    for (int k0 = 0; k0 < KLD; k0 += 32) {
        bf16x8 a0 = *(const bf16x8*)(Ab + (m0 + lrow)      * KLD + k0 + koff);
        bf16x8 a1 = *(const bf16x8*)(Ab + (m0 + 16 + lrow) * KLD + k0 + koff);
        bf16x8 bb[4];
#pragma unroll
        for (int j = 0; j < 4; ++j)
            bb[j] = *(const bf16x8*)(Bb + (size_t)(n0 + j * 16 + lrow) * KLD + k0 + koff);
#pragma unroll
        for (int j = 0; j < 4; ++j) {
            acc[0][j] = __builtin_amdgcn_mfma_f32_16x16x32_bf16(a0, bb[j], acc[0][j], 0, 0, 0);
            acc[1][j] = __builtin_amdgcn_mfma_f32_16x16x32_bf16(a1, bb[j], acc[1][j], 0, 0, 0);
        }
    }
    const float* __restrict__ Hs = H + (size_t)b * DP * NP;
    float* __restrict__ Ob = Out + (size_t)b * DP * NP;
    const float inv_n = 1.0f / (float)NSEQ;
    const int ccol  = lane & 15;
    const int crow0 = (lane >> 4) * 4;
#pragma unroll
    for (int i = 0; i < 2; ++i)
#pragma unroll
        for (int j = 0; j < 4; ++j)
#pragma unroll
            for (int r = 0; r < 4; ++r) {
                const int gd = m0 + i * 16 + crow0 + r;
                const int gt = n0 + j * 16 + ccol;
                if (gd < DP && gt < NP) {
                    const size_t idx = (size_t)gd * NP + gt;
                    Ob[idx] = Hs[idx] + inv_n * acc[i][j][r];
                }
            }
}

extern "C" void kernel_launch(void* const* d_in, const int* in_sizes, int n_in,
                              void* d_out, int out_size, void* d_ws, size_t ws_size,
                              hipStream_t stream) {
    const float* H = (const float*)d_in[0];
    const float* P = (const float*)d_in[1];
    const float* Q = (const float*)d_in[2];
    float* out = (float*)d_out;

    __hip_bfloat16* Hb  = (__hip_bfloat16*)d_ws;                   // 16*320*2048
    __hip_bfloat16* Hbt = Hb  + (size_t)NB * HROWS * 2048;         // 16*2112*288
    __hip_bfloat16* G   = Hbt + (size_t)NB * TROWS * KLD;          // 16*288*288
    __hip_bfloat16* Kb  = G   + (size_t)NB * KLD * KLD;            // 16*288*288
    __hip_bfloat16* Pb  = Kb  + (size_t)NB * KLD * KLD;            // 288*288
    __hip_bfloat16* Qt  = Pb  + (size_t)KLD * KLD;                 // 288*288

    conv_pq<<<dim3(5, 5, 2),   256, 0, stream>>>(P, Q, Pb, Qt);
    conv_h <<<dim3(33, 5, NB), 256, 0, stream>>>(H, Hb, Hbt);
    // G[b] = H-hat @ H-hat^T  (split-K x8, 512-thread blocks, in-block reduce)
    gram_sk8<<<dim3(81, NB), 512, 0, stream>>>(Hb, G);
    // Kb[b] = P @ G[b] @ Q  (fused two-stage, W through LDS)
    pgq_kernel<<<dim3(9, NB), 256, 0, stream>>>(Pb, Qt, G, Kb);
    // out = H + (Kb @ H) / n
    attn_mfma<<<dim3(1188), 256, 0, stream>>>(Kb, Hbt, H, out);
}

// Round 6
// 211.650 us; speedup vs baseline: 1.0502x; 1.0201x over previous
//
#include <hip/hip_runtime.h>
#include <hip/hip_bf16.h>

#define DP    257
#define NP    2049
#define NSEQ  2048
#define NB    16
#define KLD   288          // padded k-dim / leading dim for small matrices (9*32)
#define HROWS 320          // padded rows for Hb
#define TROWS 2112         // padded t rows for Hbt (33*64)

typedef __attribute__((ext_vector_type(8))) short bf16x8;
typedef __attribute__((ext_vector_type(4))) short bf16x4;
typedef __attribute__((ext_vector_type(4))) float f32x4;

// ---------------------------------------------------------------------------
// Convert H -> Hb (row-major bf16, 320 rows x 2048 cols, = masked H-hat)
//           -> Hbt (transposed bf16, 2112 rows x 288 cols, zero-padded)
// ---------------------------------------------------------------------------
__global__ __launch_bounds__(256) void conv_h(const float* __restrict__ H,
                                              __hip_bfloat16* __restrict__ Hb,
                                              __hip_bfloat16* __restrict__ Hbt) {
    const int b  = blockIdx.z;
    const int t0 = blockIdx.x * 64;
    const int e0 = blockIdx.y * 64;
    const float* __restrict__ Hs = H + (size_t)b * DP * NP;
    __hip_bfloat16* __restrict__ Hbb  = Hb  + (size_t)b * HROWS * 2048;
    __hip_bfloat16* __restrict__ Hbtb = Hbt + (size_t)b * TROWS * KLD;

    __shared__ float tile[64][65];

    const int tl = threadIdx.x & 63;
    const int er = threadIdx.x >> 6;
#pragma unroll
    for (int r = 0; r < 16; ++r) {
        const int el = er + r * 4;        // 0..63
        const int ge = e0 + el;
        const int gt = t0 + tl;
        float v = 0.f;
        if (ge < DP && gt < NP) v = Hs[(size_t)ge * NP + gt];
        tile[el][tl] = v;
        if (ge < HROWS && gt < 2048) Hbb[(size_t)ge * 2048 + gt] = __float2bfloat16(v);
    }
    __syncthreads();
#pragma unroll
    for (int r = 0; r < 16; ++r) {
        const int ttl = er + r * 4;       // t-local
        const int gt = t0 + ttl;
        const int ge = e0 + tl;           // e-local = lane -> contiguous writes
        if (gt < TROWS && ge < KLD)
            Hbtb[(size_t)gt * KLD + ge] = __float2bfloat16(tile[tl][ttl]);
    }
}

// ---------------------------------------------------------------------------
// Pb[m][k] = P[m][k] (bf16, zero-padded to 288x288); Qt[n][k] = Q[k][n]
// ---------------------------------------------------------------------------
__global__ __launch_bounds__(256) void conv_pq(const float* __restrict__ P,
                                               const float* __restrict__ Q,
                                               __hip_bfloat16* __restrict__ Pb,
                                               __hip_bfloat16* __restrict__ Qt) {
    const int c0 = blockIdx.x * 64;
    const int r0 = blockIdx.y * 64;
    const int tl = threadIdx.x & 63;
    const int rr = threadIdx.x >> 6;
    __shared__ float tile[64][65];

    if (blockIdx.z == 0) {
#pragma unroll
        for (int r = 0; r < 16; ++r) {
            const int m = r0 + rr + r * 4;
            const int k = c0 + tl;
            float v = (m < DP && k < DP) ? P[m * DP + k] : 0.f;
            if (m < KLD && k < KLD) Pb[m * KLD + k] = __float2bfloat16(v);
        }
    } else {
#pragma unroll
        for (int r = 0; r < 16; ++r) {
            const int k = r0 + rr + r * 4;
            const int n = c0 + tl;
            float v = (k < DP && n < DP) ? Q[k * DP + n] : 0.f;
            tile[k - r0][n - c0] = v;
        }
        __syncthreads();
#pragma unroll
        for (int r = 0; r < 16; ++r) {
            const int k = r0 + tl;
            const int n = c0 + rr + r * 4;
            if (n < KLD && k < KLD) Qt[n * KLD + k] = __float2bfloat16(tile[tl][n - c0]);
        }
    }
}

// ---------------------------------------------------------------------------
// G[b] = Hb[b] @ Hb[b]^T  with split-K x8: 512-thread blocks, one block per
// 32x32 output tile; wave s covers k in [s*256, s*256+256) (8 steps);
// 8 partial tiles summed via LDS; packed bf16x2 stores.
// ---------------------------------------------------------------------------
__global__ __launch_bounds__(512) void gram_sk8(const __hip_bfloat16* __restrict__ Hb,
                                                __hip_bfloat16* __restrict__ G) {
    const int b  = blockIdx.y;
    const int tm = blockIdx.x / 9;
    const int tn = blockIdx.x % 9;
    const int s    = threadIdx.x >> 6;     // k-split id = wave id (0..7)
    const int lane = threadIdx.x & 63;
    const int lrow = lane & 15;
    const int koff = (lane >> 4) * 8;
    const short* __restrict__ base = (const short*)(Hb + (size_t)b * HROWS * 2048);
    const int m0 = tm * 32, n0 = tn * 32;

    __shared__ float red[8][32][32];       // 32 KB

    f32x4 acc[2][2] = {};
    const int kbeg = s * 256;
#pragma unroll 4
    for (int k0 = kbeg; k0 < kbeg + 256; k0 += 32) {
        bf16x8 a0 = *(const bf16x8*)(base + (size_t)(m0 + lrow)      * 2048 + k0 + koff);
        bf16x8 a1 = *(const bf16x8*)(base + (size_t)(m0 + 16 + lrow) * 2048 + k0 + koff);
        bf16x8 c0 = *(const bf16x8*)(base + (size_t)(n0 + lrow)      * 2048 + k0 + koff);
        bf16x8 c1 = *(const bf16x8*)(base + (size_t)(n0 + 16 + lrow) * 2048 + k0 + koff);
        acc[0][0] = __builtin_amdgcn_mfma_f32_16x16x32_bf16(a0, c0, acc[0][0], 0, 0, 0);
        acc[0][1] = __builtin_amdgcn_mfma_f32_16x16x32_bf16(a0, c1, acc[0][1], 0, 0, 0);
        acc[1][0] = __builtin_amdgcn_mfma_f32_16x16x32_bf16(a1, c0, acc[1][0], 0, 0, 0);
        acc[1][1] = __builtin_amdgcn_mfma_f32_16x16x32_bf16(a1, c1, acc[1][1], 0, 0, 0);
    }

    const int ccol  = lane & 15;
    const int crow0 = (lane >> 4) * 4;
#pragma unroll
    for (int i = 0; i < 2; ++i)
#pragma unroll
        for (int j = 0; j < 2; ++j)
#pragma unroll
            for (int r = 0; r < 4; ++r)
                red[s][i * 16 + crow0 + r][j * 16 + ccol] = acc[i][j][r];
    __syncthreads();

    // 512 threads: each sums 2 consecutive cols of one row across the 8 splits
    const int row = threadIdx.x >> 4;           // 0..31
    const int c2  = (threadIdx.x & 15) * 2;     // 0..30
    float s0 = 0.f, s1 = 0.f;
#pragma unroll
    for (int ss = 0; ss < 8; ++ss) {
        s0 += red[ss][row][c2];
        s1 += red[ss][row][c2 + 1];
    }
    const int gm = m0 + row;
    const int gn = n0 + c2;
    const float v0 = (gm < DP && gn     < DP) ? s0 : 0.f;
    const float v1 = (gm < DP && gn + 1 < DP) ? s1 : 0.f;
    __hip_bfloat16 o0 = __float2bfloat16(v0);
    __hip_bfloat16 o1 = __float2bfloat16(v1);
    const unsigned int pk = (unsigned int)*(unsigned short*)&o0 |
                            ((unsigned int)*(unsigned short*)&o1 << 16);
    __hip_bfloat16* __restrict__ Gb = G + (size_t)b * KLD * KLD;
    *(unsigned int*)&Gb[gm * KLD + gn] = pk;
}

// ---------------------------------------------------------------------------
// C[b][m][n] = sum_k A[m][k] * B[n][k]  (K=288, ld=288), split-K x4:
// one block per 32x32 tile, wave s takes k-steps {s, s+4, s+8}; LDS reduce.
// ---------------------------------------------------------------------------
__global__ __launch_bounds__(256) void mm_sk4(const __hip_bfloat16* __restrict__ A,
                                              const __hip_bfloat16* __restrict__ B,
                                              __hip_bfloat16* __restrict__ C,
                                              int strideA, int strideB) {
    const int b  = blockIdx.y;
    const int tm = blockIdx.x / 9;
    const int tn = blockIdx.x % 9;
    const int s    = threadIdx.x >> 6;     // 0..3
    const int lane = threadIdx.x & 63;
    const int lrow = lane & 15;
    const int koff = (lane >> 4) * 8;
    const short* __restrict__ Ab = (const short*)(A + (size_t)b * strideA);
    const short* __restrict__ Bb = (const short*)(B + (size_t)b * strideB);
    const int m0 = tm * 32, n0 = tn * 32;

    __shared__ float red[4][32][32];       // 16 KB

    f32x4 acc[2][2] = {};
    for (int kt = s; kt < 9; kt += 4) {
        const int k0 = kt * 32;
        bf16x8 a0 = *(const bf16x8*)(Ab + (m0 + lrow)      * KLD + k0 + koff);
        bf16x8 a1 = *(const bf16x8*)(Ab + (m0 + 16 + lrow) * KLD + k0 + koff);
        bf16x8 c0 = *(const bf16x8*)(Bb + (n0 + lrow)      * KLD + k0 + koff);
        bf16x8 c1 = *(const bf16x8*)(Bb + (n0 + 16 + lrow) * KLD + k0 + koff);
        acc[0][0] = __builtin_amdgcn_mfma_f32_16x16x32_bf16(a0, c0, acc[0][0], 0, 0, 0);
        acc[0][1] = __builtin_amdgcn_mfma_f32_16x16x32_bf16(a0, c1, acc[0][1], 0, 0, 0);
        acc[1][0] = __builtin_amdgcn_mfma_f32_16x16x32_bf16(a1, c0, acc[1][0], 0, 0, 0);
        acc[1][1] = __builtin_amdgcn_mfma_f32_16x16x32_bf16(a1, c1, acc[1][1], 0, 0, 0);
    }

    const int ccol  = lane & 15;
    const int crow0 = (lane >> 4) * 4;
#pragma unroll
    for (int i = 0; i < 2; ++i)
#pragma unroll
        for (int j = 0; j < 2; ++j)
#pragma unroll
            for (int r = 0; r < 4; ++r)
                red[s][i * 16 + crow0 + r][j * 16 + ccol] = acc[i][j][r];
    __syncthreads();

    // 256 threads: each sums 4 consecutive cols of one row across the 4 splits
    const int row = threadIdx.x >> 3;          // 0..31
    const int c4  = (threadIdx.x & 7) * 4;     // 0..28
    float4 v0 = *(const float4*)&red[0][row][c4];
    float4 v1 = *(const float4*)&red[1][row][c4];
    float4 v2 = *(const float4*)&red[2][row][c4];
    float4 v3 = *(const float4*)&red[3][row][c4];
    float sum[4] = {v0.x + v1.x + v2.x + v3.x,
                    v0.y + v1.y + v2.y + v3.y,
                    v0.z + v1.z + v2.z + v3.z,
                    v0.w + v1.w + v2.w + v3.w};
    const int gm = m0 + row;
    const int gn = n0 + c4;
    __hip_bfloat16 o[4];
#pragma unroll
    for (int t = 0; t < 4; ++t) {
        const float v = (gm < DP && (gn + t) < DP) ? sum[t] : 0.f;
        o[t] = __float2bfloat16(v);
    }
    __hip_bfloat16* __restrict__ Cb = C + (size_t)b * KLD * KLD;
    *(bf16x4*)&Cb[gm * KLD + gn] = *(const bf16x4*)o;
}

// ---------------------------------------------------------------------------
// out[b][d][t] = H[b][d][t] + (1/n) * sum_e Kb[d][e] * Hbt[t][e]
// One wave per 32(d) x 64(t) tile. Epilogue routes the accumulator through
// LDS and does row-wise alignment-fixed float4 read-modify-writes.
// ---------------------------------------------------------------------------
__global__ __launch_bounds__(256) void attn_mfma(const __hip_bfloat16* __restrict__ Kb,
                                                 const __hip_bfloat16* __restrict__ Hbt,
                                                 const float* __restrict__ H,
                                                 float* __restrict__ Out) {
    const int w    = threadIdx.x >> 6;
    const int gw   = blockIdx.x * 4 + w;
    const int b    = gw / 297;            // 297 = 9 (d-tiles of 32) * 33 (t-tiles of 64)
    const int tile = gw % 297;
    const int td = tile / 33, tt = tile % 33;
    const int lane = threadIdx.x & 63;
    const int lrow = lane & 15;
    const int koff = (lane >> 4) * 8;
    const short* __restrict__ Ab = (const short*)(Kb  + (size_t)b * KLD * KLD);
    const short* __restrict__ Bb = (const short*)(Hbt + (size_t)b * TROWS * KLD);
    const int m0 = td * 32, n0 = tt * 64;

    __shared__ float lds[4][32][68];      // 34 KB

    f32x4 acc[2][4] = {};
#pragma unroll 3
    for (int k0 = 0; k0 < KLD; k0 += 32) {
        bf16x8 a0 = *(const bf16x8*)(Ab + (m0 + lrow)      * KLD + k0 + koff);
        bf16x8 a1 = *(const bf16x8*)(Ab + (m0 + 16 + lrow) * KLD + k0 + koff);
        bf16x8 bb[4];
#pragma unroll
        for (int j = 0; j < 4; ++j)
            bb[j] = *(const bf16x8*)(Bb + (size_t)(n0 + j * 16 + lrow) * KLD + k0 + koff);
#pragma unroll
        for (int j = 0; j < 4; ++j) {
            acc[0][j] = __builtin_amdgcn_mfma_f32_16x16x32_bf16(a0, bb[j], acc[0][j], 0, 0, 0);
            acc[1][j] = __builtin_amdgcn_mfma_f32_16x16x32_bf16(a1, bb[j], acc[1][j], 0, 0, 0);
        }
    }

    // stage accumulator to LDS (per-wave region)
    const int ccol  = lane & 15;
    const int crow0 = (lane >> 4) * 4;
#pragma unroll
    for (int i = 0; i < 2; ++i)
#pragma unroll
        for (int j = 0; j < 4; ++j)
#pragma unroll
            for (int r = 0; r < 4; ++r)
                lds[w][i * 16 + crow0 + r][j * 16 + ccol] = acc[i][j][r];
    __syncthreads();

    // row-wise vectorized RMW: lane -> (row = lane>>1, half = lane&1), 32 t each
    const float* __restrict__ Hs = H + (size_t)b * DP * NP;
    float* __restrict__ Ob = Out + (size_t)b * DP * NP;
    const float inv_n = 1.0f / (float)NSEQ;
    const int row = lane >> 1;
    const int hh  = lane & 1;
    const int gd  = m0 + row;
    const int gt0 = n0 + hh * 32;
    if (gd < DP) {
        const float* __restrict__ src = &lds[w][row][hh * 32];
        const size_t base = (size_t)gd * NP;
        if (gt0 + 31 < NP) {
            const int amod = (int)((base + gt0) & 3);
            const int lead = (4 - amod) & 3;
            int i = 0;
            for (; i < lead; ++i) {
                const size_t idx = base + gt0 + i;
                Ob[idx] = Hs[idx] + inv_n * src[i];
            }
            for (; i + 3 < 32; i += 4) {
                const size_t idx = base + gt0 + i;
                float4 hv = *(const float4*)&Hs[idx];
                float4 ov;
                ov.x = hv.x + inv_n * src[i];
                ov.y = hv.y + inv_n * src[i + 1];
                ov.z = hv.z + inv_n * src[i + 2];
                ov.w = hv.w + inv_n * src[i + 3];
                *(float4*)&Ob[idx] = ov;
            }
            for (; i < 32; ++i) {
                const size_t idx = base + gt0 + i;
                Ob[idx] = Hs[idx] + inv_n * src[i];
            }
        } else {
            for (int i = 0; i < 32; ++i) {
                const int gt = gt0 + i;
                if (gt < NP) {
                    const size_t idx = base + gt;
                    Ob[idx] = Hs[idx] + inv_n * src[i];
                }
            }
        }
    }
}

extern "C" void kernel_launch(void* const* d_in, const int* in_sizes, int n_in,
                              void* d_out, int out_size, void* d_ws, size_t ws_size,
                              hipStream_t stream) {
    const float* H = (const float*)d_in[0];
    const float* P = (const float*)d_in[1];
    const float* Q = (const float*)d_in[2];
    float* out = (float*)d_out;

    __hip_bfloat16* Hb  = (__hip_bfloat16*)d_ws;                   // 16*320*2048
    __hip_bfloat16* Hbt = Hb  + (size_t)NB * HROWS * 2048;         // 16*2112*288
    __hip_bfloat16* G   = Hbt + (size_t)NB * TROWS * KLD;          // 16*288*288
    __hip_bfloat16* W   = G   + (size_t)NB * KLD * KLD;            // 16*288*288
    __hip_bfloat16* Kb  = W   + (size_t)NB * KLD * KLD;            // 16*288*288
    __hip_bfloat16* Pb  = Kb  + (size_t)NB * KLD * KLD;            // 288*288
    __hip_bfloat16* Qt  = Pb  + (size_t)KLD * KLD;                 // 288*288

    conv_pq<<<dim3(5, 5, 2),   256, 0, stream>>>(P, Q, Pb, Qt);
    conv_h <<<dim3(33, 5, NB), 256, 0, stream>>>(H, Hb, Hbt);
    // G[b] = H-hat @ H-hat^T  (split-K x8, 512-thread blocks, in-block reduce)
    gram_sk8<<<dim3(81, NB), 512, 0, stream>>>(Hb, G);
    // W[b] = P @ G[b]   (B-frags = G rows, valid by symmetry of G)
    mm_sk4<<<dim3(81, NB), 256, 0, stream>>>(Pb, G, W, 0, KLD * KLD);
    // Kb[b] = W[b] @ Q  (B-frags = Qt rows)
    mm_sk4<<<dim3(81, NB), 256, 0, stream>>>(W, Qt, Kb, KLD * KLD, 0);
    // out = H + (Kb @ H) / n
    attn_mfma<<<dim3(1188), 256, 0, stream>>>(Kb, Hbt, H, out);
}

// Round 7
// 194.830 us; speedup vs baseline: 1.1409x; 1.0863x over previous
//
#include <hip/hip_runtime.h>
#include <hip/hip_bf16.h>

#define DP    257
#define NP    2049
#define NSEQ  2048
#define NB    16
#define KLD   288          // padded k-dim / leading dim for small matrices (9*32)
#define HROWS 320          // padded rows for Hb
#define TROWS 2304         // padded t rows for Hbt (9*256)
#define KPAD  40           // LDS row pitch (shorts): 80 B = 16B-aligned, 2-way banks max

typedef __attribute__((ext_vector_type(8))) short bf16x8;
typedef __attribute__((ext_vector_type(4))) short bf16x4;
typedef __attribute__((ext_vector_type(4))) float f32x4;

// ---------------------------------------------------------------------------
// Convert H -> Hb (row-major bf16, 320 x 2048, = masked H-hat)
//           -> Hbt (transposed bf16, 2304 x 288, zero-padded)
// ---------------------------------------------------------------------------
__global__ __launch_bounds__(256) void conv_h(const float* __restrict__ H,
                                              __hip_bfloat16* __restrict__ Hb,
                                              __hip_bfloat16* __restrict__ Hbt) {
    const int b  = blockIdx.z;
    const int t0 = blockIdx.x * 64;
    const int e0 = blockIdx.y * 64;
    const float* __restrict__ Hs = H + (size_t)b * DP * NP;
    __hip_bfloat16* __restrict__ Hbb  = Hb  + (size_t)b * HROWS * 2048;
    __hip_bfloat16* __restrict__ Hbtb = Hbt + (size_t)b * TROWS * KLD;

    __shared__ float tile[64][65];

    const int tl = threadIdx.x & 63;
    const int er = threadIdx.x >> 6;
#pragma unroll
    for (int r = 0; r < 16; ++r) {
        const int el = er + r * 4;        // 0..63
        const int ge = e0 + el;
        const int gt = t0 + tl;
        float v = 0.f;
        if (ge < DP && gt < NP) v = Hs[(size_t)ge * NP + gt];
        tile[el][tl] = v;
        if (ge < HROWS && gt < 2048) Hbb[(size_t)ge * 2048 + gt] = __float2bfloat16(v);
    }
    __syncthreads();
#pragma unroll
    for (int r = 0; r < 16; ++r) {
        const int ttl = er + r * 4;       // t-local
        const int gt = t0 + ttl;
        const int ge = e0 + tl;           // e-local = lane -> contiguous writes
        if (gt < TROWS && ge < KLD)
            Hbtb[(size_t)gt * KLD + ge] = __float2bfloat16(tile[tl][ttl]);
    }
}

// ---------------------------------------------------------------------------
// Pb[m][k] = P[m][k] (bf16, zero-padded to 288x288); Qt[n][k] = Q[k][n]
// ---------------------------------------------------------------------------
__global__ __launch_bounds__(256) void conv_pq(const float* __restrict__ P,
                                               const float* __restrict__ Q,
                                               __hip_bfloat16* __restrict__ Pb,
                                               __hip_bfloat16* __restrict__ Qt) {
    const int c0 = blockIdx.x * 64;
    const int r0 = blockIdx.y * 64;
    const int tl = threadIdx.x & 63;
    const int rr = threadIdx.x >> 6;
    __shared__ float tile[64][65];

    if (blockIdx.z == 0) {
#pragma unroll
        for (int r = 0; r < 16; ++r) {
            const int m = r0 + rr + r * 4;
            const int k = c0 + tl;
            float v = (m < DP && k < DP) ? P[m * DP + k] : 0.f;
            if (m < KLD && k < KLD) Pb[m * KLD + k] = __float2bfloat16(v);
        }
    } else {
#pragma unroll
        for (int r = 0; r < 16; ++r) {
            const int k = r0 + rr + r * 4;
            const int n = c0 + tl;
            float v = (k < DP && n < DP) ? Q[k * DP + n] : 0.f;
            tile[k - r0][n - c0] = v;
        }
        __syncthreads();
#pragma unroll
        for (int r = 0; r < 16; ++r) {
            const int k = r0 + tl;
            const int n = c0 + rr + r * 4;
            if (n < KLD && k < KLD) Qt[n * KLD + k] = __float2bfloat16(tile[tl][n - c0]);
        }
    }
}

// ---------------------------------------------------------------------------
// G[b] = Hb[b] @ Hb[b]^T, staged. Block = 64x64 output tile, 512 threads.
// Waves 0-3 compute K-half 0 (4 quadrants), waves 4-7 K-half 1.
// Per k-step (32): tiles staged to LDS (16B/lane), frags via ds_read_b128,
// double-buffered. Final: 2-way LDS reduce (red aliases staging memory).
// ---------------------------------------------------------------------------
__global__ __launch_bounds__(512, 4) void gram_staged(const __hip_bfloat16* __restrict__ Hb,
                                                      __hip_bfloat16* __restrict__ G) {
    const int b  = blockIdx.y;
    const int tm = blockIdx.x / 5;
    const int tn = blockIdx.x % 5;
    const int m0 = tm * 64, n0 = tn * 64;
    const int tid = threadIdx.x;
    const int wave = tid >> 6, lane = tid & 63;
    const int lrow = lane & 15, kq = (lane >> 4) * 8;
    const int hw = wave >> 2;            // compute half
    const int q  = wave & 3;             // quadrant
    const int mh = (q & 1) * 32, nh = (q >> 1) * 32;
    // staging role: 256-thread halves
    const int hs = tid >> 8;             // staging half
    const int t2 = tid & 255;
    const int sr = t2 >> 2;              // 0..63
    const int sc = (t2 & 3) * 8;         // 0,8,16,24

    __shared__ __align__(16) char smem[2 * 2 * 2 * 64 * KPAD * 2];  // 40960 B
    short* As = (short*)smem;                    // [buf][h][64][KPAD]
    short* Bs = (short*)(smem + 2 * 2 * 64 * KPAD * 2);
    float* red = (float*)smem;                   // [8][32][32] (reused after loop)

    const short* __restrict__ base = (const short*)(Hb + (size_t)b * HROWS * 2048);

    auto aoff = [&](int buf, int h, int r) { return ((buf * 2 + h) * 64 + r) * KPAD; };

    f32x4 acc[2][2] = {};

    // stage step 0
    {
        const int kb = hs * 1024;
        *(bf16x8*)&As[aoff(0, hs, sr) + sc] = *(const bf16x8*)(base + (size_t)(m0 + sr) * 2048 + kb + sc);
        *(bf16x8*)&Bs[aoff(0, hs, sr) + sc] = *(const bf16x8*)(base + (size_t)(n0 + sr) * 2048 + kb + sc);
    }
    __syncthreads();

    for (int kt = 0; kt < 32; ++kt) {
        const int cur = kt & 1, nxt = cur ^ 1;
        if (kt + 1 < 32) {
            const int kb = hs * 1024 + (kt + 1) * 32;
            *(bf16x8*)&As[aoff(nxt, hs, sr) + sc] = *(const bf16x8*)(base + (size_t)(m0 + sr) * 2048 + kb + sc);
            *(bf16x8*)&Bs[aoff(nxt, hs, sr) + sc] = *(const bf16x8*)(base + (size_t)(n0 + sr) * 2048 + kb + sc);
        }
        bf16x8 a0 = *(const bf16x8*)&As[aoff(cur, hw, mh + lrow) + kq];
        bf16x8 a1 = *(const bf16x8*)&As[aoff(cur, hw, mh + 16 + lrow) + kq];
        bf16x8 b0 = *(const bf16x8*)&Bs[aoff(cur, hw, nh + lrow) + kq];
        bf16x8 b1 = *(const bf16x8*)&Bs[aoff(cur, hw, nh + 16 + lrow) + kq];
        acc[0][0] = __builtin_amdgcn_mfma_f32_16x16x32_bf16(a0, b0, acc[0][0], 0, 0, 0);
        acc[0][1] = __builtin_amdgcn_mfma_f32_16x16x32_bf16(a0, b1, acc[0][1], 0, 0, 0);
        acc[1][0] = __builtin_amdgcn_mfma_f32_16x16x32_bf16(a1, b0, acc[1][0], 0, 0, 0);
        acc[1][1] = __builtin_amdgcn_mfma_f32_16x16x32_bf16(a1, b1, acc[1][1], 0, 0, 0);
        __syncthreads();
    }

    // dump partials: red[wave][32][32]
    const int ccol  = lane & 15;
    const int crow0 = (lane >> 4) * 4;
#pragma unroll
    for (int i = 0; i < 2; ++i)
#pragma unroll
        for (int j = 0; j < 2; ++j)
#pragma unroll
            for (int r = 0; r < 4; ++r)
                red[((wave * 32) + i * 16 + crow0 + r) * 32 + j * 16 + ccol] = acc[i][j][r];
    __syncthreads();

    // combine halves: 512 threads -> quadrant q2 = tid>>7, 8 cols each
    const int q2  = tid >> 7;
    const int t7  = tid & 127;
    const int row = t7 >> 2;
    const int c8  = (t7 & 3) * 8;
    const int gm = m0 + (q2 & 1) * 32 + row;
    const int gn = n0 + (q2 >> 1) * 32 + c8;
    if (gm < KLD && gn < KLD) {
        __hip_bfloat16 o[8];
#pragma unroll
        for (int t = 0; t < 8; ++t) {
            const float v = red[((q2 * 32) + row) * 32 + c8 + t] +
                            red[(((q2 + 4) * 32) + row) * 32 + c8 + t];
            o[t] = __float2bfloat16((gm < DP && (gn + t) < DP) ? v : 0.f);
        }
        __hip_bfloat16* __restrict__ Gb = G + (size_t)b * KLD * KLD;
        *(bf16x8*)&Gb[gm * KLD + gn] = *(const bf16x8*)o;
    }
}

// ---------------------------------------------------------------------------
// C[b][m][n] = sum_k A[m][k] * B[n][k]  (K=288, ld=288), split-K x4,
// one block per 32x32 tile; LDS reduce. (unchanged from R6)
// ---------------------------------------------------------------------------
__global__ __launch_bounds__(256) void mm_sk4(const __hip_bfloat16* __restrict__ A,
                                              const __hip_bfloat16* __restrict__ B,
                                              __hip_bfloat16* __restrict__ C,
                                              int strideA, int strideB) {
    const int b  = blockIdx.y;
    const int tm = blockIdx.x / 9;
    const int tn = blockIdx.x % 9;
    const int s    = threadIdx.x >> 6;
    const int lane = threadIdx.x & 63;
    const int lrow = lane & 15;
    const int koff = (lane >> 4) * 8;
    const short* __restrict__ Ab = (const short*)(A + (size_t)b * strideA);
    const short* __restrict__ Bb = (const short*)(B + (size_t)b * strideB);
    const int m0 = tm * 32, n0 = tn * 32;

    __shared__ float red[4][32][32];

    f32x4 acc[2][2] = {};
    for (int kt = s; kt < 9; kt += 4) {
        const int k0 = kt * 32;
        bf16x8 a0 = *(const bf16x8*)(Ab + (m0 + lrow)      * KLD + k0 + koff);
        bf16x8 a1 = *(const bf16x8*)(Ab + (m0 + 16 + lrow) * KLD + k0 + koff);
        bf16x8 c0 = *(const bf16x8*)(Bb + (n0 + lrow)      * KLD + k0 + koff);
        bf16x8 c1 = *(const bf16x8*)(Bb + (n0 + 16 + lrow) * KLD + k0 + koff);
        acc[0][0] = __builtin_amdgcn_mfma_f32_16x16x32_bf16(a0, c0, acc[0][0], 0, 0, 0);
        acc[0][1] = __builtin_amdgcn_mfma_f32_16x16x32_bf16(a0, c1, acc[0][1], 0, 0, 0);
        acc[1][0] = __builtin_amdgcn_mfma_f32_16x16x32_bf16(a1, c0, acc[1][0], 0, 0, 0);
        acc[1][1] = __builtin_amdgcn_mfma_f32_16x16x32_bf16(a1, c1, acc[1][1], 0, 0, 0);
    }

    const int ccol  = lane & 15;
    const int crow0 = (lane >> 4) * 4;
#pragma unroll
    for (int i = 0; i < 2; ++i)
#pragma unroll
        for (int j = 0; j < 2; ++j)
#pragma unroll
            for (int r = 0; r < 4; ++r)
                red[s][i * 16 + crow0 + r][j * 16 + ccol] = acc[i][j][r];
    __syncthreads();

    const int row = threadIdx.x >> 3;
    const int c4  = (threadIdx.x & 7) * 4;
    float4 v0 = *(const float4*)&red[0][row][c4];
    float4 v1 = *(const float4*)&red[1][row][c4];
    float4 v2 = *(const float4*)&red[2][row][c4];
    float4 v3 = *(const float4*)&red[3][row][c4];
    float sum[4] = {v0.x + v1.x + v2.x + v3.x,
                    v0.y + v1.y + v2.y + v3.y,
                    v0.z + v1.z + v2.z + v3.z,
                    v0.w + v1.w + v2.w + v3.w};
    const int gm = m0 + row;
    const int gn = n0 + c4;
    __hip_bfloat16 o[4];
#pragma unroll
    for (int t = 0; t < 4; ++t) {
        const float v = (gm < DP && (gn + t) < DP) ? sum[t] : 0.f;
        o[t] = __float2bfloat16(v);
    }
    __hip_bfloat16* __restrict__ Cb = C + (size_t)b * KLD * KLD;
    *(bf16x4*)&Cb[gm * KLD + gn] = *(const bf16x4*)o;
}

// ---------------------------------------------------------------------------
// out[b][d][t] = H[b][d][t] + (1/n) * sum_e Kb[d][e] * Hbt[t][e]
// Staged: block = 64 d x 256 t, 4 waves (each 64d x 64t), 9 double-buffered
// e-chunks of 32. A/B tiles in LDS, frags via ds_read_b128.
// ---------------------------------------------------------------------------
__global__ __launch_bounds__(256, 3) void attn_staged(const __hip_bfloat16* __restrict__ Kb,
                                                      const __hip_bfloat16* __restrict__ Hbt,
                                                      const float* __restrict__ H,
                                                      float* __restrict__ Out) {
    const int b  = blockIdx.z;
    const int d0 = blockIdx.y * 64;
    const int t0 = blockIdx.x * 256;
    const int tid = threadIdx.x;
    const int wave = tid >> 6, lane = tid & 63;
    const int lrow = lane & 15, kq = (lane >> 4) * 8;
    const int sr = tid >> 2;            // 0..63
    const int sc = (tid & 3) * 8;       // 0,8,16,24

    __shared__ __align__(16) short As[2][64][KPAD];    // 10 KB
    __shared__ __align__(16) short Bs[2][256][KPAD];   // 40 KB

    const short* __restrict__ Ka = (const short*)(Kb  + (size_t)b * KLD * KLD);
    const short* __restrict__ Ta = (const short*)(Hbt + (size_t)b * TROWS * KLD);

    int rA = d0 + sr; if (rA > KLD - 1) rA = KLD - 1;   // clamp (d-tile 4 pad rows)

    f32x4 acc[4][4] = {};

    // stage chunk 0
    *(bf16x8*)&As[0][sr][sc] = *(const bf16x8*)(Ka + (size_t)rA * KLD + sc);
#pragma unroll
    for (int c = 0; c < 4; ++c)
        *(bf16x8*)&Bs[0][sr + 64 * c][sc] = *(const bf16x8*)(Ta + (size_t)(t0 + sr + 64 * c) * KLD + sc);
    __syncthreads();

    for (int kt = 0; kt < 9; ++kt) {
        const int cur = kt & 1, nxt = cur ^ 1;
        if (kt + 1 < 9) {
            const int e0 = (kt + 1) * 32;
            *(bf16x8*)&As[nxt][sr][sc] = *(const bf16x8*)(Ka + (size_t)rA * KLD + e0 + sc);
#pragma unroll
            for (int c = 0; c < 4; ++c)
                *(bf16x8*)&Bs[nxt][sr + 64 * c][sc] = *(const bf16x8*)(Ta + (size_t)(t0 + sr + 64 * c) * KLD + e0 + sc);
        }
        bf16x8 af[4], bfr[4];
#pragma unroll
        for (int i = 0; i < 4; ++i) af[i]  = *(const bf16x8*)&As[cur][i * 16 + lrow][kq];
#pragma unroll
        for (int j = 0; j < 4; ++j) bfr[j] = *(const bf16x8*)&Bs[cur][wave * 64 + j * 16 + lrow][kq];
#pragma unroll
        for (int i = 0; i < 4; ++i)
#pragma unroll
            for (int j = 0; j < 4; ++j)
                acc[i][j] = __builtin_amdgcn_mfma_f32_16x16x32_bf16(af[i], bfr[j], acc[i][j], 0, 0, 0);
        __syncthreads();
    }

    // epilogue: direct scatter (quad writes 64 B contiguous t)
    const float* __restrict__ Hs = H + (size_t)b * DP * NP;
    float* __restrict__ Ob = Out + (size_t)b * DP * NP;
    const float inv_n = 1.0f / (float)NSEQ;
    const int ccol  = lane & 15;
    const int crow0 = (lane >> 4) * 4;
#pragma unroll
    for (int i = 0; i < 4; ++i)
#pragma unroll
        for (int j = 0; j < 4; ++j)
#pragma unroll
            for (int r = 0; r < 4; ++r) {
                const int gd = d0 + i * 16 + crow0 + r;
                const int gt = t0 + wave * 64 + j * 16 + ccol;
                if (gd < DP && gt < NP) {
                    const size_t idx = (size_t)gd * NP + gt;
                    Ob[idx] = Hs[idx] + inv_n * acc[i][j][r];
                }
            }
}

extern "C" void kernel_launch(void* const* d_in, const int* in_sizes, int n_in,
                              void* d_out, int out_size, void* d_ws, size_t ws_size,
                              hipStream_t stream) {
    const float* H = (const float*)d_in[0];
    const float* P = (const float*)d_in[1];
    const float* Q = (const float*)d_in[2];
    float* out = (float*)d_out;

    __hip_bfloat16* Hb  = (__hip_bfloat16*)d_ws;                   // 16*320*2048
    __hip_bfloat16* Hbt = Hb  + (size_t)NB * HROWS * 2048;         // 16*2304*288
    __hip_bfloat16* G   = Hbt + (size_t)NB * TROWS * KLD;          // 16*288*288
    __hip_bfloat16* Pb  = G   + (size_t)NB * KLD * KLD;            // 288*288
    __hip_bfloat16* Qt  = Pb  + (size_t)KLD * KLD;                 // 288*288
    // W and Kb alias Hb's region (Hb is dead after gram_staged)
    __hip_bfloat16* W   = Hb;
    __hip_bfloat16* Kb  = Hb + (size_t)NB * KLD * KLD;

    conv_pq<<<dim3(5, 5, 2),   256, 0, stream>>>(P, Q, Pb, Qt);
    conv_h <<<dim3(36, 5, NB), 256, 0, stream>>>(H, Hb, Hbt);
    // G[b] = H-hat @ H-hat^T  (staged 64x64 tiles, in-block split-K x2)
    gram_staged<<<dim3(25, NB), 512, 0, stream>>>(Hb, G);
    // W[b] = P @ G[b]   (B-frags = G rows, valid by symmetry of G)
    mm_sk4<<<dim3(81, NB), 256, 0, stream>>>(Pb, G, W, 0, KLD * KLD);
    // Kb[b] = W[b] @ Q  (B-frags = Qt rows)
    mm_sk4<<<dim3(81, NB), 256, 0, stream>>>(W, Qt, Kb, KLD * KLD, 0);
    // out = H + (Kb @ H) / n  (staged)
    attn_staged<<<dim3(9, 5, NB), 256, 0, stream>>>(Kb, Hbt, H, out);
}

// Round 8
// 191.972 us; speedup vs baseline: 1.1578x; 1.0149x over previous
//
#include <hip/hip_runtime.h>
#include <hip/hip_bf16.h>

#define DP     257
#define NP     2049
#define NSEQ   2048
#define NB     16
#define KLD    288         // pitch for small matrices (shorts)
#define HROWS  320         // padded rows for Hb
#define TPITCH 320         // Hbt pitch in shorts: 640 B = 5 full 128B lines
#define TROWS  2176        // padded t rows for Hbt (17*128)
#define KPAD   40          // LDS row pitch (shorts)

typedef __attribute__((ext_vector_type(8))) short bf16x8;
typedef __attribute__((ext_vector_type(4))) short bf16x4;
typedef __attribute__((ext_vector_type(4))) float f32x4;

// ---------------------------------------------------------------------------
// Convert H -> Hb (row-major bf16, 320 x 2048, = masked H-hat)
//           -> Hbt (transposed bf16, 2176 x 320-pitch, zero-padded)
// ---------------------------------------------------------------------------
__global__ __launch_bounds__(256) void conv_h(const float* __restrict__ H,
                                              __hip_bfloat16* __restrict__ Hb,
                                              __hip_bfloat16* __restrict__ Hbt) {
    const int b  = blockIdx.z;
    const int t0 = blockIdx.x * 64;
    const int e0 = blockIdx.y * 64;
    const float* __restrict__ Hs = H + (size_t)b * DP * NP;
    __hip_bfloat16* __restrict__ Hbb  = Hb  + (size_t)b * HROWS * 2048;
    __hip_bfloat16* __restrict__ Hbtb = Hbt + (size_t)b * TROWS * TPITCH;

    __shared__ float tile[64][65];

    const int tl = threadIdx.x & 63;
    const int er = threadIdx.x >> 6;
#pragma unroll
    for (int r = 0; r < 16; ++r) {
        const int el = er + r * 4;        // 0..63
        const int ge = e0 + el;
        const int gt = t0 + tl;
        float v = 0.f;
        if (ge < DP && gt < NP) v = Hs[(size_t)ge * NP + gt];
        tile[el][tl] = v;
        if (ge < HROWS && gt < 2048) Hbb[(size_t)ge * 2048 + gt] = __float2bfloat16(v);
    }
    __syncthreads();
#pragma unroll
    for (int r = 0; r < 16; ++r) {
        const int ttl = er + r * 4;       // t-local
        const int gt = t0 + ttl;
        const int ge = e0 + tl;           // e-local = lane -> contiguous writes
        if (gt < TROWS && ge < TPITCH) {
            const float v = (ge < KLD) ? tile[tl][ttl] : 0.f;
            Hbtb[(size_t)gt * TPITCH + ge] = __float2bfloat16(v);
        }
    }
}

// ---------------------------------------------------------------------------
// Pb[m][k] = P[m][k] (bf16, zero-padded to 288x288); Qt[n][k] = Q[k][n]
// ---------------------------------------------------------------------------
__global__ __launch_bounds__(256) void conv_pq(const float* __restrict__ P,
                                               const float* __restrict__ Q,
                                               __hip_bfloat16* __restrict__ Pb,
                                               __hip_bfloat16* __restrict__ Qt) {
    const int c0 = blockIdx.x * 64;
    const int r0 = blockIdx.y * 64;
    const int tl = threadIdx.x & 63;
    const int rr = threadIdx.x >> 6;
    __shared__ float tile[64][65];

    if (blockIdx.z == 0) {
#pragma unroll
        for (int r = 0; r < 16; ++r) {
            const int m = r0 + rr + r * 4;
            const int k = c0 + tl;
            float v = (m < DP && k < DP) ? P[m * DP + k] : 0.f;
            if (m < KLD && k < KLD) Pb[m * KLD + k] = __float2bfloat16(v);
        }
    } else {
#pragma unroll
        for (int r = 0; r < 16; ++r) {
            const int k = r0 + rr + r * 4;
            const int n = c0 + tl;
            float v = (k < DP && n < DP) ? Q[k * DP + n] : 0.f;
            tile[k - r0][n - c0] = v;
        }
        __syncthreads();
#pragma unroll
        for (int r = 0; r < 16; ++r) {
            const int k = r0 + tl;
            const int n = c0 + rr + r * 4;
            if (n < KLD && k < KLD) Qt[n * KLD + k] = __float2bfloat16(tile[tl][n - c0]);
        }
    }
}

// ---------------------------------------------------------------------------
// G[b] = Hb[b] @ Hb[b]^T, staged 64x64 tiles, 512 threads, split-K x2.
// (unchanged from R7)
// ---------------------------------------------------------------------------
__global__ __launch_bounds__(512, 4) void gram_staged(const __hip_bfloat16* __restrict__ Hb,
                                                      __hip_bfloat16* __restrict__ G) {
    const int b  = blockIdx.y;
    const int tm = blockIdx.x / 5;
    const int tn = blockIdx.x % 5;
    const int m0 = tm * 64, n0 = tn * 64;
    const int tid = threadIdx.x;
    const int wave = tid >> 6, lane = tid & 63;
    const int lrow = lane & 15, kq = (lane >> 4) * 8;
    const int hw = wave >> 2;            // compute half
    const int q  = wave & 3;             // quadrant
    const int mh = (q & 1) * 32, nh = (q >> 1) * 32;
    const int hs = tid >> 8;             // staging half
    const int t2 = tid & 255;
    const int sr = t2 >> 2;              // 0..63
    const int sc = (t2 & 3) * 8;         // 0,8,16,24

    __shared__ __align__(16) char smem[2 * 2 * 2 * 64 * KPAD * 2];  // 40960 B
    short* As = (short*)smem;                    // [buf][h][64][KPAD]
    short* Bs = (short*)(smem + 2 * 2 * 64 * KPAD * 2);
    float* red = (float*)smem;                   // [8][32][32] (reused after loop)

    const short* __restrict__ base = (const short*)(Hb + (size_t)b * HROWS * 2048);

    auto aoff = [&](int buf, int h, int r) { return ((buf * 2 + h) * 64 + r) * KPAD; };

    f32x4 acc[2][2] = {};

    {
        const int kb = hs * 1024;
        *(bf16x8*)&As[aoff(0, hs, sr) + sc] = *(const bf16x8*)(base + (size_t)(m0 + sr) * 2048 + kb + sc);
        *(bf16x8*)&Bs[aoff(0, hs, sr) + sc] = *(const bf16x8*)(base + (size_t)(n0 + sr) * 2048 + kb + sc);
    }
    __syncthreads();

    for (int kt = 0; kt < 32; ++kt) {
        const int cur = kt & 1, nxt = cur ^ 1;
        if (kt + 1 < 32) {
            const int kb = hs * 1024 + (kt + 1) * 32;
            *(bf16x8*)&As[aoff(nxt, hs, sr) + sc] = *(const bf16x8*)(base + (size_t)(m0 + sr) * 2048 + kb + sc);
            *(bf16x8*)&Bs[aoff(nxt, hs, sr) + sc] = *(const bf16x8*)(base + (size_t)(n0 + sr) * 2048 + kb + sc);
        }
        bf16x8 a0 = *(const bf16x8*)&As[aoff(cur, hw, mh + lrow) + kq];
        bf16x8 a1 = *(const bf16x8*)&As[aoff(cur, hw, mh + 16 + lrow) + kq];
        bf16x8 b0 = *(const bf16x8*)&Bs[aoff(cur, hw, nh + lrow) + kq];
        bf16x8 b1 = *(const bf16x8*)&Bs[aoff(cur, hw, nh + 16 + lrow) + kq];
        acc[0][0] = __builtin_amdgcn_mfma_f32_16x16x32_bf16(a0, b0, acc[0][0], 0, 0, 0);
        acc[0][1] = __builtin_amdgcn_mfma_f32_16x16x32_bf16(a0, b1, acc[0][1], 0, 0, 0);
        acc[1][0] = __builtin_amdgcn_mfma_f32_16x16x32_bf16(a1, b0, acc[1][0], 0, 0, 0);
        acc[1][1] = __builtin_amdgcn_mfma_f32_16x16x32_bf16(a1, b1, acc[1][1], 0, 0, 0);
        __syncthreads();
    }

    const int ccol  = lane & 15;
    const int crow0 = (lane >> 4) * 4;
#pragma unroll
    for (int i = 0; i < 2; ++i)
#pragma unroll
        for (int j = 0; j < 2; ++j)
#pragma unroll
            for (int r = 0; r < 4; ++r)
                red[((wave * 32) + i * 16 + crow0 + r) * 32 + j * 16 + ccol] = acc[i][j][r];
    __syncthreads();

    const int q2  = tid >> 7;
    const int t7  = tid & 127;
    const int row = t7 >> 2;
    const int c8  = (t7 & 3) * 8;
    const int gm = m0 + (q2 & 1) * 32 + row;
    const int gn = n0 + (q2 >> 1) * 32 + c8;
    if (gm < KLD && gn < KLD) {
        __hip_bfloat16 o[8];
#pragma unroll
        for (int t = 0; t < 8; ++t) {
            const float v = red[((q2 * 32) + row) * 32 + c8 + t] +
                            red[(((q2 + 4) * 32) + row) * 32 + c8 + t];
            o[t] = __float2bfloat16((gm < DP && (gn + t) < DP) ? v : 0.f);
        }
        __hip_bfloat16* __restrict__ Gb = G + (size_t)b * KLD * KLD;
        *(bf16x8*)&Gb[gm * KLD + gn] = *(const bf16x8*)o;
    }
}

// ---------------------------------------------------------------------------
// C[b][m][n] = sum_k A[m][k] * B[n][k]  (K=288, ld=288), split-K x4.
// (unchanged from R6)
// ---------------------------------------------------------------------------
__global__ __launch_bounds__(256) void mm_sk4(const __hip_bfloat16* __restrict__ A,
                                              const __hip_bfloat16* __restrict__ B,
                                              __hip_bfloat16* __restrict__ C,
                                              int strideA, int strideB) {
    const int b  = blockIdx.y;
    const int tm = blockIdx.x / 9;
    const int tn = blockIdx.x % 9;
    const int s    = threadIdx.x >> 6;
    const int lane = threadIdx.x & 63;
    const int lrow = lane & 15;
    const int koff = (lane >> 4) * 8;
    const short* __restrict__ Ab = (const short*)(A + (size_t)b * strideA);
    const short* __restrict__ Bb = (const short*)(B + (size_t)b * strideB);
    const int m0 = tm * 32, n0 = tn * 32;

    __shared__ float red[4][32][32];

    f32x4 acc[2][2] = {};
    for (int kt = s; kt < 9; kt += 4) {
        const int k0 = kt * 32;
        bf16x8 a0 = *(const bf16x8*)(Ab + (m0 + lrow)      * KLD + k0 + koff);
        bf16x8 a1 = *(const bf16x8*)(Ab + (m0 + 16 + lrow) * KLD + k0 + koff);
        bf16x8 c0 = *(const bf16x8*)(Bb + (n0 + lrow)      * KLD + k0 + koff);
        bf16x8 c1 = *(const bf16x8*)(Bb + (n0 + 16 + lrow) * KLD + k0 + koff);
        acc[0][0] = __builtin_amdgcn_mfma_f32_16x16x32_bf16(a0, c0, acc[0][0], 0, 0, 0);
        acc[0][1] = __builtin_amdgcn_mfma_f32_16x16x32_bf16(a0, c1, acc[0][1], 0, 0, 0);
        acc[1][0] = __builtin_amdgcn_mfma_f32_16x16x32_bf16(a1, c0, acc[1][0], 0, 0, 0);
        acc[1][1] = __builtin_amdgcn_mfma_f32_16x16x32_bf16(a1, c1, acc[1][1], 0, 0, 0);
    }

    const int ccol  = lane & 15;
    const int crow0 = (lane >> 4) * 4;
#pragma unroll
    for (int i = 0; i < 2; ++i)
#pragma unroll
        for (int j = 0; j < 2; ++j)
#pragma unroll
            for (int r = 0; r < 4; ++r)
                red[s][i * 16 + crow0 + r][j * 16 + ccol] = acc[i][j][r];
    __syncthreads();

    const int row = threadIdx.x >> 3;
    const int c4  = (threadIdx.x & 7) * 4;
    float4 v0 = *(const float4*)&red[0][row][c4];
    float4 v1 = *(const float4*)&red[1][row][c4];
    float4 v2 = *(const float4*)&red[2][row][c4];
    float4 v3 = *(const float4*)&red[3][row][c4];
    float sum[4] = {v0.x + v1.x + v2.x + v3.x,
                    v0.y + v1.y + v2.y + v3.y,
                    v0.z + v1.z + v2.z + v3.z,
                    v0.w + v1.w + v2.w + v3.w};
    const int gm = m0 + row;
    const int gn = n0 + c4;
    __hip_bfloat16 o[4];
#pragma unroll
    for (int t = 0; t < 4; ++t) {
        const float v = (gm < DP && (gn + t) < DP) ? sum[t] : 0.f;
        o[t] = __float2bfloat16(v);
    }
    __hip_bfloat16* __restrict__ Cb = C + (size_t)b * KLD * KLD;
    *(bf16x4*)&Cb[gm * KLD + gn] = *(const bf16x4*)o;
}

// ---------------------------------------------------------------------------
// out[b][d][t] = H[b][d][t] + (1/n) * sum_e Kb[d][e] * Hbt[t][e]
// Block = 64 d x 128 t, 4 waves (each 32d x 64t). Single-buffered 15 KB LDS
// with register prefetch across the 9 e-chunks. Epilogue: acc -> LDS in
// 16-row chunks -> block-coalesced row-segment RMW of H/out.
// ---------------------------------------------------------------------------
__global__ __launch_bounds__(256, 4) void attn_v2(const __hip_bfloat16* __restrict__ Kb,
                                                  const __hip_bfloat16* __restrict__ Hbt,
                                                  const float* __restrict__ H,
                                                  float* __restrict__ Out) {
    const int b  = blockIdx.z;
    const int d0 = blockIdx.y * 64;
    const int t0 = blockIdx.x * 128;
    const int tid = threadIdx.x;
    const int wave = tid >> 6, lane = tid & 63;
    const int lrow = lane & 15, kq = (lane >> 4) * 8;
    const int dh = (wave & 1) * 32;      // wave's d-half
    const int th = (wave >> 1) * 64;     // wave's t-half
    const int sr = tid >> 2;             // 0..63
    const int sc = (tid & 3) * 8;        // 0,8,16,24

    __shared__ __align__(16) char smem[(64 + 128) * KPAD * 2];  // 15360 B
    short* As = (short*)smem;                         // [64][KPAD]
    short* Bs = (short*)(smem + 64 * KPAD * 2);       // [128][KPAD]
    float* Ped = (float*)smem;                        // [16][132] epilogue (8448 B)

    const short* __restrict__ Ka = (const short*)(Kb  + (size_t)b * KLD * KLD);
    const short* __restrict__ Ta = (const short*)(Hbt + (size_t)b * TROWS * TPITCH);

    int rA = d0 + sr; if (rA > KLD - 1) rA = KLD - 1;   // Kb rows 257..287 are zeros

    f32x4 acc[2][4] = {};

    // stage chunk 0
    bf16x8 pA  = *(const bf16x8*)(Ka + (size_t)rA * KLD + sc);
    bf16x8 pB0 = *(const bf16x8*)(Ta + (size_t)(t0 + sr) * TPITCH + sc);
    bf16x8 pB1 = *(const bf16x8*)(Ta + (size_t)(t0 + 64 + sr) * TPITCH + sc);
    *(bf16x8*)&As[sr * KPAD + sc]        = pA;
    *(bf16x8*)&Bs[sr * KPAD + sc]        = pB0;
    *(bf16x8*)&Bs[(64 + sr) * KPAD + sc] = pB1;
    __syncthreads();

    for (int kt = 0; kt < 9; ++kt) {
        if (kt < 8) {   // register prefetch of next chunk (overlaps compute)
            const int e0 = (kt + 1) * 32;
            pA  = *(const bf16x8*)(Ka + (size_t)rA * KLD + e0 + sc);
            pB0 = *(const bf16x8*)(Ta + (size_t)(t0 + sr) * TPITCH + e0 + sc);
            pB1 = *(const bf16x8*)(Ta + (size_t)(t0 + 64 + sr) * TPITCH + e0 + sc);
        }
        bf16x8 af0 = *(const bf16x8*)&As[(dh + lrow) * KPAD + kq];
        bf16x8 af1 = *(const bf16x8*)&As[(dh + 16 + lrow) * KPAD + kq];
        bf16x8 bfr[4];
#pragma unroll
        for (int j = 0; j < 4; ++j)
            bfr[j] = *(const bf16x8*)&Bs[(th + j * 16 + lrow) * KPAD + kq];
#pragma unroll
        for (int j = 0; j < 4; ++j) {
            acc[0][j] = __builtin_amdgcn_mfma_f32_16x16x32_bf16(af0, bfr[j], acc[0][j], 0, 0, 0);
            acc[1][j] = __builtin_amdgcn_mfma_f32_16x16x32_bf16(af1, bfr[j], acc[1][j], 0, 0, 0);
        }
        __syncthreads();
        if (kt < 8) {
            *(bf16x8*)&As[sr * KPAD + sc]        = pA;
            *(bf16x8*)&Bs[sr * KPAD + sc]        = pB0;
            *(bf16x8*)&Bs[(64 + sr) * KPAD + sc] = pB1;
            __syncthreads();
        }
    }

    // epilogue: 4 chunks of 16 d-rows through LDS, coalesced RMW
    const float* __restrict__ Hs = H + (size_t)b * DP * NP;
    float* __restrict__ Ob = Out + (size_t)b * DP * NP;
    const float inv_n = 1.0f / (float)NSEQ;
    const int ccol  = lane & 15;
    const int crow0 = (lane >> 4) * 4;

#pragma unroll
    for (int c = 0; c < 4; ++c) {
        // waves whose d-half matches this chunk dump their i = (c&1) frags
        if ((wave & 1) == (c >> 1)) {
            const int i = c & 1;
#pragma unroll
            for (int j = 0; j < 4; ++j)
#pragma unroll
                for (int r = 0; r < 4; ++r)
                    Ped[(crow0 + r) * 132 + th + j * 16 + ccol] = acc[i][j][r];
        }
        __syncthreads();
        // RMW 16 rows x 128 cols: 2 passes of 8 rows; 32 lanes x 16B contiguous
#pragma unroll
        for (int p = 0; p < 2; ++p) {
            const int row = (tid >> 5) + p * 8;
            const int col = (tid & 31) * 4;
            const int gd = d0 + c * 16 + row;
            if (gd < DP) {
                const float* src = &Ped[row * 132 + col];
                const size_t base = (size_t)gd * NP;
#pragma unroll
                for (int cc = 0; cc < 4; ++cc) {
                    const int gt = t0 + col + cc;
                    if (gt < NP) {
                        const size_t idx = base + gt;
                        Ob[idx] = Hs[idx] + inv_n * src[cc];
                    }
                }
            }
        }
        __syncthreads();
    }
}

extern "C" void kernel_launch(void* const* d_in, const int* in_sizes, int n_in,
                              void* d_out, int out_size, void* d_ws, size_t ws_size,
                              hipStream_t stream) {
    const float* H = (const float*)d_in[0];
    const float* P = (const float*)d_in[1];
    const float* Q = (const float*)d_in[2];
    float* out = (float*)d_out;

    __hip_bfloat16* Hb  = (__hip_bfloat16*)d_ws;                   // 16*320*2048
    __hip_bfloat16* Hbt = Hb  + (size_t)NB * HROWS * 2048;         // 16*2176*320
    __hip_bfloat16* G   = Hbt + (size_t)NB * TROWS * TPITCH;       // 16*288*288
    __hip_bfloat16* Pb  = G   + (size_t)NB * KLD * KLD;            // 288*288
    __hip_bfloat16* Qt  = Pb  + (size_t)KLD * KLD;                 // 288*288
    // W and Kb alias Hb's region (Hb is dead after gram_staged)
    __hip_bfloat16* W   = Hb;
    __hip_bfloat16* Kb  = Hb + (size_t)NB * KLD * KLD;

    conv_pq<<<dim3(5, 5, 2),   256, 0, stream>>>(P, Q, Pb, Qt);
    conv_h <<<dim3(34, 5, NB), 256, 0, stream>>>(H, Hb, Hbt);
    // G[b] = H-hat @ H-hat^T  (staged 64x64 tiles, in-block split-K x2)
    gram_staged<<<dim3(25, NB), 512, 0, stream>>>(Hb, G);
    // W[b] = P @ G[b]   (B-frags = G rows, valid by symmetry of G)
    mm_sk4<<<dim3(81, NB), 256, 0, stream>>>(Pb, G, W, 0, KLD * KLD);
    // Kb[b] = W[b] @ Q  (B-frags = Qt rows)
    mm_sk4<<<dim3(81, NB), 256, 0, stream>>>(W, Qt, Kb, KLD * KLD, 0);
    // out = H + (Kb @ H) / n
    attn_v2<<<dim3(17, 5, NB), 256, 0, stream>>>(Kb, Hbt, H, out);
}